// Round 3
// baseline (173.258 us; speedup 1.0000x reference)
//
#include <hip/hip_runtime.h>
#include <hip/hip_bf16.h>

#define NN 646
#define FF 32768
#define HH 64
#define LL 128
#define TOT (NN*HH)          // 41344
#define OUTTOT (NN*LL)       // 82688
#define WT_STRIDE (FF + 32)  // padded bf16 row
#define KSPLIT 32
#define MT 41                // ceil(646/16)

typedef float f32x4 __attribute__((ext_vector_type(4)));
typedef short short8 __attribute__((ext_vector_type(8)));

__device__ __forceinline__ unsigned short f2bf(float f) {
  __hip_bfloat16 h = __float2bfloat16(f);
  return __builtin_bit_cast(unsigned short, h);
}
__device__ __forceinline__ short8 pack8(float4 u, float4 v) {
  short8 r;
  r[0] = (short)f2bf(u.x); r[1] = (short)f2bf(u.y);
  r[2] = (short)f2bf(u.z); r[3] = (short)f2bf(u.w);
  r[4] = (short)f2bf(v.x); r[5] = (short)f2bf(v.y);
  r[6] = (short)f2bf(v.z); r[7] = (short)f2bf(v.w);
  return r;
}

// ---- K0: transpose+convert [W1|LPw] -> wt bf16 [128][WT_STRIDE]
__global__ __launch_bounds__(256) void k_wt(const float* __restrict__ W1,
                                            const float* __restrict__ LPw,
                                            unsigned short* __restrict__ wt) {
  __shared__ float t[64][129];
  int k0 = blockIdx.x * 64;
  for (int idx = threadIdx.x; idx < 64 * 128; idx += 256) {
    int kk = idx >> 7, n = idx & 127;
    float v = (n < 64) ? W1[(size_t)(k0 + kk) * 64 + n]
                       : LPw[(size_t)(k0 + kk) * 64 + (n - 64)];
    t[kk][n] = v;
  }
  __syncthreads();
  for (int idx = threadIdx.x; idx < 64 * 128; idx += 256) {
    int kk = idx & 63, n = idx >> 6;
    wt[(size_t)n * WT_STRIDE + k0 + kk] = f2bf(t[kk][n]);
  }
}

// ---- K1: degrees + dinv + CSR offsets + placement, one block
__global__ __launch_bounds__(1024) void k_prep(const int* __restrict__ e32, int E,
                                               float* __restrict__ dinv,
                                               int* __restrict__ offsets,
                                               int* __restrict__ srcs) {
  __shared__ int cnt[1024];
  __shared__ int scn[1024];
  __shared__ int orred;
  int tid = threadIdx.x;
  if (tid == 0) orred = 0;
  cnt[tid] = 0;
  __syncthreads();
  if (tid < E && e32[2 * tid + 1] != 0) atomicOr(&orred, 1);
  __syncthreads();
  bool i64 = (orred == 0);
  const int* rp = e32;
  const int* cp = i64 ? (e32 + 2 * (size_t)E) : (e32 + E);
  int st = i64 ? 2 : 1;
  for (int e = tid; e < E; e += 1024) atomicAdd(&cnt[cp[(size_t)e * st]], 1);
  __syncthreads();
  int v = cnt[tid];
  scn[tid] = v;
  __syncthreads();
  for (int d = 1; d < 1024; d <<= 1) {
    int t = (tid >= d) ? scn[tid - d] : 0;
    __syncthreads();
    scn[tid] += t;
    __syncthreads();
  }
  int off = scn[tid] - v;  // exclusive prefix
  __syncthreads();
  cnt[tid] = off;          // becomes absolute cursor
  if (tid < NN) { offsets[tid] = off; dinv[tid] = rsqrtf((float)(v + 1)); }
  if (tid == 0) offsets[NN] = E;
  __syncthreads();
  for (int e = tid; e < E; e += 1024) {
    int r = rp[(size_t)e * st];
    int c = cp[(size_t)e * st];
    int p = atomicAdd(&cnt[c], 1);
    srcs[p] = r;
  }
}

// ---- K2: split-K GEMM, 16m x 128n tiles, fenced 2-deep register pipeline
__global__ __launch_bounds__(256, 3) void k_gemm(const float* __restrict__ x,
                                                 const unsigned short* __restrict__ wt,
                                                 float* __restrict__ partial) {
  int p = blockIdx.x;                 // 0..1311
  int xcd = p & 7, slot = p >> 3;     // bijective: 1312 = 8 * 164, 164 = 4*41
  int ks = xcd + 8 * (slot / MT);     // all blocks of one ks land on one XCD
  int mt = slot % MT;
  int tid = threadIdx.x;
  int w = tid >> 6, l = tid & 63;
  int lr = l & 15, g = l >> 4;
  int row = mt * 16 + lr; if (row > NN - 1) row = NN - 1;
  const float* xp = x + (size_t)row * FF + ks * 1024 + g * 8;
  const unsigned short* wp0 = wt + (size_t)(w * 32 + lr) * WT_STRIDE + ks * 1024 + g * 8;
  const unsigned short* wp1 = wp0 + (size_t)16 * WT_STRIDE;
  f32x4 ac0 = {0.f, 0.f, 0.f, 0.f}, ac1 = ac0;

  float4 A0[8], A1[8];
  short8 B0[8], B1[8];

  auto LOADQ = [&](float4* Ab, short8* Bb, int q) {
    const float* ap = xp + q * 128;
    const unsigned short* bp0 = wp0 + q * 128;
    const unsigned short* bp1 = wp1 + q * 128;
#pragma unroll
    for (int c = 0; c < 4; ++c) {
      Ab[2 * c]     = *reinterpret_cast<const float4*>(ap + c * 32);
      Ab[2 * c + 1] = *reinterpret_cast<const float4*>(ap + c * 32 + 4);
      Bb[2 * c]     = *reinterpret_cast<const short8*>(bp0 + c * 32);
      Bb[2 * c + 1] = *reinterpret_cast<const short8*>(bp1 + c * 32);
    }
  };
  auto COMPQ = [&](const float4* Ab, const short8* Bb) {
#pragma unroll
    for (int c = 0; c < 4; ++c) {
      short8 av = pack8(Ab[2 * c], Ab[2 * c + 1]);
      ac0 = __builtin_amdgcn_mfma_f32_16x16x32_bf16(av, Bb[2 * c],     ac0, 0, 0, 0);
      ac1 = __builtin_amdgcn_mfma_f32_16x16x32_bf16(av, Bb[2 * c + 1], ac1, 0, 0, 0);
    }
  };

  LOADQ(A0, B0, 0);
  LOADQ(A1, B1, 1);
  __builtin_amdgcn_sched_barrier(0);
#pragma unroll
  for (int q = 0; q < 8; ++q) {
    if (q & 1) {
      COMPQ(A1, B1);
      __builtin_amdgcn_sched_barrier(0);
      if (q + 2 < 8) { LOADQ(A1, B1, q + 2); __builtin_amdgcn_sched_barrier(0); }
    } else {
      COMPQ(A0, B0);
      __builtin_amdgcn_sched_barrier(0);
      if (q + 2 < 8) { LOADQ(A0, B0, q + 2); __builtin_amdgcn_sched_barrier(0); }
    }
  }

  float* pp = partial + (size_t)ks * OUTTOT;
  int nb = w * 32 + lr;
#pragma unroll
  for (int j = 0; j < 4; ++j) {
    int m = mt * 16 + g * 4 + j;
    if (m < NN) {
      pp[m * LL + nb]      = ac0[j];
      pp[m * LL + nb + 16] = ac1[j];
    }
  }
}

// ---- K3: reduce partials (float4), add LPb to cols 64..127
__global__ __launch_bounds__(256) void k_red(const float* __restrict__ partial,
                                             const float* __restrict__ LPb,
                                             float* __restrict__ hcat) {
  int i4 = blockIdx.x * 256 + threadIdx.x;
  if (i4 * 4 >= OUTTOT) return;
  f32x4 s = {0.f, 0.f, 0.f, 0.f};
#pragma unroll 8
  for (int ks = 0; ks < KSPLIT; ++ks)
    s += *reinterpret_cast<const f32x4*>(partial + (size_t)ks * OUTTOT + i4 * 4);
  int n = (i4 * 4) & 127;
  if (n & 64) s += *reinterpret_cast<const f32x4*>(LPb + (n - 64));
  *reinterpret_cast<f32x4*>(hcat + i4 * 4) = s;
}

// ---- K4: GCN1 gather
__global__ __launch_bounds__(256) void k_agg1(const int* __restrict__ offsets,
                                              const int* __restrict__ srcs,
                                              const float* __restrict__ dinv,
                                              const float* __restrict__ hcat,
                                              float* __restrict__ gb) {
  int c = blockIdx.x;
  int j = threadIdx.x & 63, qt = threadIdx.x >> 6;
  int o0 = offsets[c], o1 = offsets[c + 1];
  float acc = 0.f;
  for (int i = o0 + qt; i < o1; i += 4) {
    int r = srcs[i];
    acc += hcat[r * LL + j] * dinv[r];
  }
  __shared__ float red[4][64];
  red[qt][j] = acc;
  __syncthreads();
  if (qt == 0)
    gb[c * HH + j] = (red[0][j] + red[1][j] + red[2][j] + red[3][j]) * dinv[c];
}

// ---- K5: res + GCN1 + b1 + self-loop, SiLU, partial LN stats
__global__ __launch_bounds__(256) void k_silu(const float* __restrict__ hcat,
                                              const float* __restrict__ gb,
                                              const float* __restrict__ b1,
                                              const float* __restrict__ dinv,
                                              float* __restrict__ hn,
                                              float* __restrict__ stats) {
  int idx = blockIdx.x * 256 + threadIdx.x;
  float sum = 0.f, sq = 0.f;
  if (idx < TOT) {
    int m = idx >> 6, j = idx & 63;
    float di = dinv[m];
    float t = hcat[(m << 7) + 64 + j] + b1[j] + gb[idx] + hcat[(m << 7) + j] * di * di;
    float s = t / (1.f + __expf(-t));
    hn[idx] = s;
    sum = s; sq = s * s;
  }
#pragma unroll
  for (int o = 32; o; o >>= 1) { sum += __shfl_down(sum, o); sq += __shfl_down(sq, o); }
  __shared__ float ls[4], lq[4];
  int wv = threadIdx.x >> 6;
  if ((threadIdx.x & 63) == 0) { ls[wv] = sum; lq[wv] = sq; }
  __syncthreads();
  if (threadIdx.x == 0) {
    atomicAdd(&stats[0], ls[0] + ls[1] + ls[2] + ls[3]);
    atomicAdd(&stats[1], lq[0] + lq[1] + lq[2] + lq[3]);
  }
}

// ---- K6: normalize
__global__ __launch_bounds__(256) void k_norm(float* __restrict__ hn,
                                              const float* __restrict__ stats) {
  int idx = blockIdx.x * 256 + threadIdx.x;
  float mu = stats[0] * (1.f / TOT);
  float var = stats[1] * (1.f / TOT) - mu * mu;
  float rs = rsqrtf(var + 1e-5f);
  if (idx < TOT) hn[idx] = (hn[idx] - mu) * rs;
}

// ---- K7: hw[i][j] = (hn[i]@W2)[j] * dinv[i]
__global__ __launch_bounds__(256) void k_g2(const float* __restrict__ hn,
                                            const float* __restrict__ W2,
                                            const float* __restrict__ dinv,
                                            float* __restrict__ hw) {
  __shared__ float w2s[HH * LL];
  for (int i = threadIdx.x; i < HH * LL; i += 256) w2s[i] = W2[i];
  __syncthreads();
  int idx = blockIdx.x * 256 + threadIdx.x;
  int i = idx >> 7, j = idx & 127;
  float acc = 0.f;
#pragma unroll
  for (int k = 0; k < HH; ++k) acc += hn[i * HH + k] * w2s[k * LL + j];
  hw[idx] = acc * dinv[i];
}

// ---- K8: GCN2 gather + bias + self loop
__global__ __launch_bounds__(256) void k_agg2(const int* __restrict__ offsets,
                                              const int* __restrict__ srcs,
                                              const float* __restrict__ dinv,
                                              const float* __restrict__ hw,
                                              const float* __restrict__ b2,
                                              float* __restrict__ out) {
  int c = blockIdx.x;
  int j = threadIdx.x & 127, hf = threadIdx.x >> 7;
  int o0 = offsets[c], o1 = offsets[c + 1];
  float acc = 0.f;
  for (int i = o0 + hf; i < o1; i += 2) acc += hw[srcs[i] * LL + j];
  __shared__ float red[2][128];
  red[hf][j] = acc;
  __syncthreads();
  if (hf == 0)
    out[c * LL + j] = b2[j] + dinv[c] * (red[0][j] + red[1][j] + hw[c * LL + j]);
}

extern "C" void kernel_launch(void* const* d_in, const int* in_sizes, int n_in,
                              void* d_out, int out_size, void* d_ws, size_t ws_size,
                              hipStream_t stream) {
  const float* x   = (const float*)d_in[0];
  const int*   e32 = (const int*)d_in[1];
  const float* W1  = (const float*)d_in[2];
  const float* b1  = (const float*)d_in[3];
  const float* W2  = (const float*)d_in[4];
  const float* b2  = (const float*)d_in[5];
  const float* LPw = (const float*)d_in[6];
  const float* LPb = (const float*)d_in[7];
  int E = in_sizes[1] / 2;
  float* out = (float*)d_out;

  char* ws = (char*)d_ws;
  size_t wt_b   = (size_t)128 * WT_STRIDE * 2;        // 8,396,800
  size_t part_b = (size_t)KSPLIT * OUTTOT * 4;        // 10,584,064

  size_t o_partial = wt_b;
  size_t o_gb   = o_partial;                 // aliases partial (dead after k_red)
  size_t o_hn   = o_partial + 165376;
  size_t o_hw   = o_hn + 165376;
  size_t o_hcat = o_partial + part_b;
  size_t o_dinv = o_hcat + 330752;
  size_t o_offs = o_dinv + 2816;
  size_t o_srcs = o_offs + 2816;
  size_t o_stat = o_srcs + 165376;

  unsigned short* wt = (unsigned short*)ws;
  float* partial = (float*)(ws + o_partial);
  float* gb      = (float*)(ws + o_gb);
  float* hn      = (float*)(ws + o_hn);
  float* hw      = (float*)(ws + o_hw);
  float* hcat    = (float*)(ws + o_hcat);
  float* dinv    = (float*)(ws + o_dinv);
  int*   offs    = (int*)(ws + o_offs);
  int*   srcs    = (int*)(ws + o_srcs);
  float* stats   = (float*)(ws + o_stat);

  hipMemsetAsync(stats, 0, 8, stream);
  k_wt<<<FF / 64, 256, 0, stream>>>(W1, LPw, wt);
  k_prep<<<1, 1024, 0, stream>>>(e32, E, dinv, offs, srcs);
  k_gemm<<<MT * KSPLIT, 256, 0, stream>>>(x, wt, partial);
  k_red<<<(OUTTOT / 4 + 255) / 256, 256, 0, stream>>>(partial, LPb, hcat);
  k_agg1<<<NN, 256, 0, stream>>>(offs, srcs, dinv, hcat, gb);
  k_silu<<<(TOT + 255) / 256, 256, 0, stream>>>(hcat, gb, b1, dinv, hn, stats);
  k_norm<<<(TOT + 255) / 256, 256, 0, stream>>>(hn, stats);
  k_g2<<<OUTTOT / 256, 256, 0, stream>>>(hn, W2, dinv, hw);
  k_agg2<<<NN, 256, 0, stream>>>(offs, srcs, dinv, hw, b2, out);
}

// Round 4
// 157.791 us; speedup vs baseline: 1.0980x; 1.0980x over previous
//
#include <hip/hip_runtime.h>
#include <hip/hip_bf16.h>

#define NN 646
#define FF 32768
#define HH 64
#define LL 128
#define TOT (NN*HH)          // 41344
#define OUTTOT (NN*LL)       // 82688
#define WT_STRIDE (FF + 32)  // padded bf16 row
#define KSPLIT 32
#define KSLICE (FF / KSPLIT) // 1024
#define NSTEP (KSLICE / 64)  // 16

typedef float f32x4 __attribute__((ext_vector_type(4)));
typedef short short8 __attribute__((ext_vector_type(8)));

__device__ __forceinline__ unsigned short f2bf(float f) {
  __hip_bfloat16 h = __float2bfloat16(f);
  return __builtin_bit_cast(unsigned short, h);
}
__device__ __forceinline__ short8 pack8(float4 u, float4 v) {
  short8 r;
  r[0] = (short)f2bf(u.x); r[1] = (short)f2bf(u.y);
  r[2] = (short)f2bf(u.z); r[3] = (short)f2bf(u.w);
  r[4] = (short)f2bf(v.x); r[5] = (short)f2bf(v.y);
  r[6] = (short)f2bf(v.z); r[7] = (short)f2bf(v.w);
  return r;
}
__device__ __forceinline__ void gload16(const void* g, void* l) {
  __builtin_amdgcn_global_load_lds(
      (const __attribute__((address_space(1))) void*)g,
      (__attribute__((address_space(3))) void*)l, 16, 0, 0);
}

// ---- K_init: blocks 0..511 transpose [W1|LPw] -> wt; block 512 builds CSR + dinv + stats=0
__global__ __launch_bounds__(256) void k_init(const float* __restrict__ W1,
                                              const float* __restrict__ LPw,
                                              unsigned short* __restrict__ wt,
                                              const int* __restrict__ e32, int E,
                                              float* __restrict__ dinv,
                                              int* __restrict__ offsets,
                                              int* __restrict__ srcs,
                                              float* __restrict__ stats) {
  if (blockIdx.x < 512) {
    __shared__ float t[64][129];
    int k0 = blockIdx.x * 64;
    for (int idx = threadIdx.x; idx < 64 * 128; idx += 256) {
      int kk = idx >> 7, n = idx & 127;
      float v = (n < 64) ? W1[(size_t)(k0 + kk) * 64 + n]
                         : LPw[(size_t)(k0 + kk) * 64 + (n - 64)];
      t[kk][n] = v;
    }
    __syncthreads();
    for (int idx = threadIdx.x; idx < 64 * 128; idx += 256) {
      int kk = idx & 63, n = idx >> 6;
      wt[(size_t)n * WT_STRIDE + k0 + kk] = f2bf(t[kk][n]);
    }
    return;
  }
  // ---- prep block (256 threads)
  __shared__ int cnt[648];
  __shared__ int wtot[4];
  __shared__ int orred;
  int tid = threadIdx.x;
  if (tid == 0) orred = 0;
  if (tid < 2) stats[tid] = 0.f;
  for (int i = tid; i < 648; i += 256) cnt[i] = 0;
  __syncthreads();
  if (e32[2 * tid + 1] != 0) atomicOr(&orred, 1);  // probe first 256 hi-words
  __syncthreads();
  bool i64 = (orred == 0);
  const int* rp = e32;
  const int* cp = i64 ? (e32 + 2 * (size_t)E) : (e32 + E);
  int st = i64 ? 2 : 1;
  for (int e = tid; e < E; e += 256) atomicAdd(&cnt[cp[(size_t)e * st]], 1);
  __syncthreads();
  // blocked exclusive scan: thread t owns [3t, 3t+3)
  int b = 3 * tid;
  int c0 = (b < NN) ? cnt[b] : 0;
  int c1 = (b + 1 < NN) ? cnt[b + 1] : 0;
  int c2 = (b + 2 < NN) ? cnt[b + 2] : 0;
  int s = c0 + c1 + c2;
  int lane = tid & 63, wv = tid >> 6;
  int run = s;
#pragma unroll
  for (int o = 1; o < 64; o <<= 1) { int v = __shfl_up(run, o); if (lane >= o) run += v; }
  if (lane == 63) wtot[wv] = run;
  __syncthreads();
  int wbase = 0;
  for (int i = 0; i < wv; ++i) wbase += wtot[i];
  int excl = wbase + run - s;
  if (b < NN)     { offsets[b]     = excl;           dinv[b]     = rsqrtf((float)(c0 + 1)); }
  if (b + 1 < NN) { offsets[b + 1] = excl + c0;      dinv[b + 1] = rsqrtf((float)(c1 + 1)); }
  if (b + 2 < NN) { offsets[b + 2] = excl + c0 + c1; dinv[b + 2] = rsqrtf((float)(c2 + 1)); }
  if (tid == 0) offsets[NN] = E;
  __syncthreads();
  if (b < NN)     cnt[b]     = excl;
  if (b + 1 < NN) cnt[b + 1] = excl + c0;
  if (b + 2 < NN) cnt[b + 2] = excl + c0 + c1;
  __syncthreads();
  for (int e = tid; e < E; e += 256) {
    int r = rp[(size_t)e * st];
    int c = cp[(size_t)e * st];
    int p = atomicAdd(&cnt[c], 1);
    srcs[p] = r;
  }
}

// ---- K_gemm: m97-style 2-phase global_load_lds pipeline, XOR-swizzled LDS
__global__ __launch_bounds__(256, 3) void k_gemm(const float* __restrict__ x,
                                                 const unsigned short* __restrict__ wt,
                                                 float* __restrict__ partial) {
  int p = blockIdx.x;                  // 672 = 8 XCDs * 84
  int xcd = p & 7, idx = p >> 3;       // idx 0..83 = 4*21
  int ks = xcd + 8 * (idx / 21);       // same-ks blocks share an XCD's L2
  int mt = idx % 21;
  int tid = threadIdx.x;
  int w = tid >> 6, l = tid & 63;
  int lr = l & 15, g = l >> 4;
  int mh = w & 1, nh = w >> 1;
  int ksbase = ks * KSLICE;

  __shared__ __align__(16) float As[2][32 * 64];            // 16 KB
  __shared__ __align__(16) unsigned short Bs[2][128 * 64];  // 32 KB

  f32x4 acc0 = {0.f, 0.f, 0.f, 0.f}, acc1 = acc0, acc2 = acc0, acc3 = acc0;
  int arow = mh * 16 + lr, arm = arow & 7;

  auto STAGE = [&](int buf, int step) {
    int kb = ksbase + step * 64;
    // A tile: 32 rows x 64 f32, 16B chunks, chunk slot = row*16 + (c ^ (row&7))
#pragma unroll
    for (int j = 0; j < 2; ++j) {
      int pp = j * 256 + tid;
      int row = pp >> 4, cc = pp & 15;
      int c = cc ^ (row & 7);
      int rowg = mt * 32 + row; if (rowg > NN - 1) rowg = NN - 1;
      gload16(x + (size_t)rowg * FF + kb + c * 4, (char*)(&As[buf][0]) + pp * 16);
    }
    // B tile: 128 rows x 64 bf16, chunk slot = row*8 + (c ^ (row&7))
#pragma unroll
    for (int j = 0; j < 4; ++j) {
      int pp = j * 256 + tid;
      int row = pp >> 3, cc = pp & 7;
      int c = cc ^ (row & 7);
      gload16(wt + (size_t)row * WT_STRIDE + kb + c * 8, (char*)(&Bs[buf][0]) + pp * 16);
    }
  };

  auto COMPUTE = [&](int buf) {
    const char* Ab = (const char*)(&As[buf][0]);
    const char* Bb = (const char*)(&Bs[buf][0]);
    int c0 = g * 2, c1 = 8 + g * 2;
    float4 lo0 = *(const float4*)(Ab + (arow * 16 + (c0 ^ arm)) * 16);
    float4 hi0 = *(const float4*)(Ab + (arow * 16 + ((c0 + 1) ^ arm)) * 16);
    float4 lo1 = *(const float4*)(Ab + (arow * 16 + (c1 ^ arm)) * 16);
    float4 hi1 = *(const float4*)(Ab + (arow * 16 + ((c1 + 1) ^ arm)) * 16);
    short8 af0 = pack8(lo0, hi0);
    short8 af1 = pack8(lo1, hi1);
#pragma unroll
    for (int nf = 0; nf < 4; ++nf) {
      int brow = nh * 64 + nf * 16 + lr;
      int brm = brow & 7;
      short8 b0 = *(const short8*)(Bb + (brow * 8 + (g ^ brm)) * 16);
      short8 b1 = *(const short8*)(Bb + (brow * 8 + ((4 + g) ^ brm)) * 16);
      f32x4* ac = (nf == 0) ? &acc0 : (nf == 1) ? &acc1 : (nf == 2) ? &acc2 : &acc3;
      *ac = __builtin_amdgcn_mfma_f32_16x16x32_bf16(af0, b0, *ac, 0, 0, 0);
      *ac = __builtin_amdgcn_mfma_f32_16x16x32_bf16(af1, b1, *ac, 0, 0, 0);
    }
  };

  STAGE(0, 0);
  asm volatile("s_waitcnt vmcnt(0)" ::: "memory");
  __builtin_amdgcn_s_barrier();
  int cur = 0;
  for (int t = 0; t < NSTEP - 1; ++t) {
    STAGE(cur ^ 1, t + 1);        // prefetch next tile (stays in flight over compute)
    COMPUTE(cur);
    asm volatile("s_waitcnt vmcnt(0)" ::: "memory");
    __builtin_amdgcn_s_barrier();
    cur ^= 1;
  }
  COMPUTE(cur);

  float* pp = partial + (size_t)ks * OUTTOT;
  int colb = nh * 64 + lr;
#pragma unroll
  for (int j = 0; j < 4; ++j) {
    int m = mt * 32 + mh * 16 + g * 4 + j;
    if (m < NN) {
      pp[m * LL + colb]      = acc0[j];
      pp[m * LL + colb + 16] = acc1[j];
      pp[m * LL + colb + 32] = acc2[j];
      pp[m * LL + colb + 48] = acc3[j];
    }
  }
}

// ---- K_red: reduce 32 partials (float4), add LPb to cols 64..127
__global__ __launch_bounds__(256) void k_red(const float* __restrict__ partial,
                                             const float* __restrict__ LPb,
                                             float* __restrict__ hcat) {
  int i4 = blockIdx.x * 256 + threadIdx.x;
  if (i4 * 4 >= OUTTOT) return;
  f32x4 s = {0.f, 0.f, 0.f, 0.f};
#pragma unroll
  for (int ks = 0; ks < KSPLIT; ++ks)
    s += *reinterpret_cast<const f32x4*>(partial + (size_t)ks * OUTTOT + i4 * 4);
  int n = (i4 * 4) & 127;
  if (n & 64) s += *reinterpret_cast<const f32x4*>(LPb + (n - 64));
  *reinterpret_cast<f32x4*>(hcat + i4 * 4) = s;
}

// ---- K_aggsilu: GCN1 gather + residual + bias + self-loop + SiLU + LN stats
__global__ __launch_bounds__(256) void k_aggsilu(const int* __restrict__ offs,
                                                 const int* __restrict__ srcs,
                                                 const float* __restrict__ dinv,
                                                 const float* __restrict__ hcat,
                                                 const float* __restrict__ b1,
                                                 float* __restrict__ hn,
                                                 float* __restrict__ stats) {
  int c = blockIdx.x;
  int j = threadIdx.x & 63, qt = threadIdx.x >> 6;
  int o0 = offs[c], o1 = offs[c + 1];
  float acc = 0.f;
  for (int i = o0 + qt; i < o1; i += 4) {
    int r = srcs[i];
    acc += hcat[r * LL + j] * dinv[r];
  }
  __shared__ float red[4][64];
  red[qt][j] = acc;
  __syncthreads();
  if (qt == 0) {
    float di = dinv[c];
    float gb = (red[0][j] + red[1][j] + red[2][j] + red[3][j]) * di;
    float t = hcat[c * LL + 64 + j] + b1[j] + gb + hcat[c * LL + j] * di * di;
    float s = t / (1.f + __expf(-t));
    hn[c * HH + j] = s;
    float sum = s, sq = s * s;
#pragma unroll
    for (int o = 32; o; o >>= 1) { sum += __shfl_down(sum, o); sq += __shfl_down(sq, o); }
    if (j == 0) { atomicAdd(&stats[0], sum); atomicAdd(&stats[1], sq); }
  }
}

// ---- K_ng2: normalize row + (hn@W2)*dinv
__global__ __launch_bounds__(128) void k_ng2(const float* __restrict__ hn,
                                             const float* __restrict__ stats,
                                             const float* __restrict__ W2,
                                             const float* __restrict__ dinv,
                                             float* __restrict__ hw) {
  int i = blockIdx.x;
  int j = threadIdx.x;
  __shared__ float hnl[64];
  float mu = stats[0] * (1.f / TOT);
  float var = stats[1] * (1.f / TOT) - mu * mu;
  float rs = rsqrtf(var + 1e-5f);
  if (j < 64) hnl[j] = (hn[i * HH + j] - mu) * rs;
  __syncthreads();
  float acc = 0.f;
#pragma unroll
  for (int k = 0; k < HH; ++k) acc += hnl[k] * W2[k * LL + j];
  hw[i * LL + j] = acc * dinv[i];
}

// ---- K_agg2: GCN2 gather + bias + self loop
__global__ __launch_bounds__(256) void k_agg2(const int* __restrict__ offs,
                                              const int* __restrict__ srcs,
                                              const float* __restrict__ dinv,
                                              const float* __restrict__ hw,
                                              const float* __restrict__ b2,
                                              float* __restrict__ out) {
  int c = blockIdx.x;
  int j = threadIdx.x & 127, hf = threadIdx.x >> 7;
  int o0 = offs[c], o1 = offs[c + 1];
  float acc = 0.f;
  for (int i = o0 + hf; i < o1; i += 2) acc += hw[srcs[i] * LL + j];
  __shared__ float red[2][128];
  red[hf][j] = acc;
  __syncthreads();
  if (hf == 0)
    out[c * LL + j] = b2[j] + dinv[c] * (red[0][j] + red[1][j] + hw[c * LL + j]);
}

extern "C" void kernel_launch(void* const* d_in, const int* in_sizes, int n_in,
                              void* d_out, int out_size, void* d_ws, size_t ws_size,
                              hipStream_t stream) {
  const float* x   = (const float*)d_in[0];
  const int*   e32 = (const int*)d_in[1];
  const float* W1  = (const float*)d_in[2];
  const float* b1  = (const float*)d_in[3];
  const float* W2  = (const float*)d_in[4];
  const float* b2  = (const float*)d_in[5];
  const float* LPw = (const float*)d_in[6];
  const float* LPb = (const float*)d_in[7];
  int E = in_sizes[1] / 2;
  float* out = (float*)d_out;

  char* ws = (char*)d_ws;
  size_t wt_b   = (size_t)128 * WT_STRIDE * 2;   // 8,396,800
  size_t part_b = (size_t)KSPLIT * OUTTOT * 4;   // 10,584,064

  size_t o_partial = wt_b;
  size_t o_hn   = o_partial;                 // aliases partial (dead after k_red)
  size_t o_hw   = o_hn + 165376;
  size_t o_hcat = o_partial + part_b;
  size_t o_dinv = o_hcat + 330752;
  size_t o_offs = o_dinv + 2816;
  size_t o_srcs = o_offs + 2816;
  size_t o_stat = o_srcs + 165376;

  unsigned short* wt = (unsigned short*)ws;
  float* partial = (float*)(ws + o_partial);
  float* hn      = (float*)(ws + o_hn);
  float* hw      = (float*)(ws + o_hw);
  float* hcat    = (float*)(ws + o_hcat);
  float* dinv    = (float*)(ws + o_dinv);
  int*   offs    = (int*)(ws + o_offs);
  int*   srcs    = (int*)(ws + o_srcs);
  float* stats   = (float*)(ws + o_stat);

  k_init<<<513, 256, 0, stream>>>(W1, LPw, wt, e32, E, dinv, offs, srcs, stats);
  k_gemm<<<21 * KSPLIT, 256, 0, stream>>>(x, wt, partial);
  k_red<<<(OUTTOT / 4 + 255) / 256, 256, 0, stream>>>(partial, LPb, hcat);
  k_aggsilu<<<NN, 256, 0, stream>>>(offs, srcs, dinv, hcat, b1, hn, stats);
  k_ng2<<<NN, 128, 0, stream>>>(hn, stats, W2, dinv, hw);
  k_agg2<<<NN, 256, 0, stream>>>(offs, srcs, dinv, hw, b2, out);
}

// Round 5
// 105.714 us; speedup vs baseline: 1.6389x; 1.4926x over previous
//
#include <hip/hip_runtime.h>
#include <hip/hip_bf16.h>

#define NN 646
#define FF 32768
#define HH 64
#define LL 128
#define TOT (NN*HH)          // 41344
#define OUTTOT (NN*LL)       // 82688
#define WT_STRIDE (FF + 32)  // padded bf16 row
#define KSPLIT 32
#define KSLICE (FF / KSPLIT) // 1024
#define NSTEP (KSLICE / 64)  // 16

typedef float f32x4 __attribute__((ext_vector_type(4)));
typedef short short8 __attribute__((ext_vector_type(8)));

__device__ __forceinline__ unsigned short f2bf(float f) {
  __hip_bfloat16 h = __float2bfloat16(f);
  return __builtin_bit_cast(unsigned short, h);
}
__device__ __forceinline__ short8 pack8(float4 u, float4 v) {
  short8 r;
  r[0] = (short)f2bf(u.x); r[1] = (short)f2bf(u.y);
  r[2] = (short)f2bf(u.z); r[3] = (short)f2bf(u.w);
  r[4] = (short)f2bf(v.x); r[5] = (short)f2bf(v.y);
  r[6] = (short)f2bf(v.z); r[7] = (short)f2bf(v.w);
  return r;
}
__device__ __forceinline__ void gload16(const void* g, void* l) {
  __builtin_amdgcn_global_load_lds(
      (const __attribute__((address_space(1))) void*)g,
      (__attribute__((address_space(3))) void*)l, 16, 0, 0);
}
// block-level edge-dtype probe: true if int64 (all sampled hi-words zero)
__device__ __forceinline__ bool probe_i64(const int* e32, int* orr) {
  if (threadIdx.x == 0) *orr = 0;
  __syncthreads();
  if (threadIdx.x < 256 && e32[2 * threadIdx.x + 1] != 0) atomicOr(orr, 1);
  __syncthreads();
  return *orr == 0;
}

// ---- K_init: blocks 0..511 transpose [W1|LPw] -> wt; blocks 512..575 count degrees
__global__ __launch_bounds__(256) void k_init(const float* __restrict__ W1,
                                              const float* __restrict__ LPw,
                                              unsigned short* __restrict__ wt,
                                              const int* __restrict__ e32, int E,
                                              int* __restrict__ cnt) {
  if (blockIdx.x < 512) {
    __shared__ float t[64][129];
    int k0 = blockIdx.x * 64;
    for (int idx = threadIdx.x; idx < 64 * 128; idx += 256) {
      int kk = idx >> 7, n = idx & 127;
      float v = (n < 64) ? W1[(size_t)(k0 + kk) * 64 + n]
                         : LPw[(size_t)(k0 + kk) * 64 + (n - 64)];
      t[kk][n] = v;
    }
    __syncthreads();
    for (int idx = threadIdx.x; idx < 64 * 128; idx += 256) {
      int kk = idx & 63, n = idx >> 6;
      wt[(size_t)n * WT_STRIDE + k0 + kk] = f2bf(t[kk][n]);
    }
    return;
  }
  __shared__ int orr;
  bool i64 = probe_i64(e32, &orr);
  const int* cp = i64 ? (e32 + 2 * (size_t)E) : (e32 + E);
  int st = i64 ? 2 : 1;
  int wid = (blockIdx.x - 512) * 256 + threadIdx.x;
  for (int e = wid; e < E; e += 64 * 256)
    atomicAdd(&cnt[cp[(size_t)e * st]], 1);
}

// ---- K_scan: offsets (exclusive scan of cnt), dinv, cursor init
__global__ __launch_bounds__(1024) void k_scan(const int* __restrict__ cnt, int E,
                                               int* __restrict__ offsets,
                                               float* __restrict__ dinv,
                                               int* __restrict__ cursor) {
  __shared__ int scn[1024];
  int tid = threadIdx.x;
  int v = (tid < NN) ? cnt[tid] : 0;
  scn[tid] = v;
  __syncthreads();
  for (int d = 1; d < 1024; d <<= 1) {
    int t = (tid >= d) ? scn[tid - d] : 0;
    __syncthreads();
    scn[tid] += t;
    __syncthreads();
  }
  if (tid < NN) {
    int off = scn[tid] - v;
    offsets[tid] = off;
    cursor[tid] = off;
    dinv[tid] = rsqrtf((float)(v + 1));
  }
  if (tid == 0) offsets[NN] = E;
}

// ---- K_place: scatter edges into CSR via global cursors
__global__ __launch_bounds__(256) void k_place(const int* __restrict__ e32, int E,
                                               int* __restrict__ cursor,
                                               int* __restrict__ srcs) {
  __shared__ int orr;
  bool i64 = probe_i64(e32, &orr);
  int e = blockIdx.x * 256 + threadIdx.x;
  if (e >= E) return;
  const int* rp = e32;
  const int* cp = i64 ? (e32 + 2 * (size_t)E) : (e32 + E);
  int st = i64 ? 2 : 1;
  int r = rp[(size_t)e * st];
  int c = cp[(size_t)e * st];
  int p = atomicAdd(&cursor[c], 1);
  srcs[p] = r;
}

// ---- K_gemm: m97-style 2-phase global_load_lds pipeline, XOR-swizzled LDS
__global__ __launch_bounds__(256, 3) void k_gemm(const float* __restrict__ x,
                                                 const unsigned short* __restrict__ wt,
                                                 float* __restrict__ partial) {
  int p = blockIdx.x;                  // 672 = 8 XCDs * 84
  int xcd = p & 7, idx = p >> 3;       // idx 0..83 = 4*21
  int ks = xcd + 8 * (idx / 21);       // same-ks blocks share an XCD's L2
  int mt = idx % 21;
  int tid = threadIdx.x;
  int w = tid >> 6, l = tid & 63;
  int lr = l & 15, g = l >> 4;
  int mh = w & 1, nh = w >> 1;
  int ksbase = ks * KSLICE;

  __shared__ __align__(16) float As[2][32 * 64];            // 16 KB
  __shared__ __align__(16) unsigned short Bs[2][128 * 64];  // 32 KB

  f32x4 acc0 = {0.f, 0.f, 0.f, 0.f}, acc1 = acc0, acc2 = acc0, acc3 = acc0;
  int arow = mh * 16 + lr, arm = arow & 7;

  auto STAGE = [&](int buf, int step) {
    int kb = ksbase + step * 64;
#pragma unroll
    for (int j = 0; j < 2; ++j) {
      int pp = j * 256 + tid;
      int row = pp >> 4, cc = pp & 15;
      int c = cc ^ (row & 7);
      int rowg = mt * 32 + row; if (rowg > NN - 1) rowg = NN - 1;
      gload16(x + (size_t)rowg * FF + kb + c * 4, (char*)(&As[buf][0]) + pp * 16);
    }
#pragma unroll
    for (int j = 0; j < 4; ++j) {
      int pp = j * 256 + tid;
      int row = pp >> 3, cc = pp & 7;
      int c = cc ^ (row & 7);
      gload16(wt + (size_t)row * WT_STRIDE + kb + c * 8, (char*)(&Bs[buf][0]) + pp * 16);
    }
  };

  auto COMPUTE = [&](int buf) {
    const char* Ab = (const char*)(&As[buf][0]);
    const char* Bb = (const char*)(&Bs[buf][0]);
    int c0 = g * 2, c1 = 8 + g * 2;
    float4 lo0 = *(const float4*)(Ab + (arow * 16 + (c0 ^ arm)) * 16);
    float4 hi0 = *(const float4*)(Ab + (arow * 16 + ((c0 + 1) ^ arm)) * 16);
    float4 lo1 = *(const float4*)(Ab + (arow * 16 + (c1 ^ arm)) * 16);
    float4 hi1 = *(const float4*)(Ab + (arow * 16 + ((c1 + 1) ^ arm)) * 16);
    short8 af0 = pack8(lo0, hi0);
    short8 af1 = pack8(lo1, hi1);
#pragma unroll
    for (int nf = 0; nf < 4; ++nf) {
      int brow = nh * 64 + nf * 16 + lr;
      int brm = brow & 7;
      short8 b0 = *(const short8*)(Bb + (brow * 8 + (g ^ brm)) * 16);
      short8 b1 = *(const short8*)(Bb + (brow * 8 + ((4 + g) ^ brm)) * 16);
      f32x4* ac = (nf == 0) ? &acc0 : (nf == 1) ? &acc1 : (nf == 2) ? &acc2 : &acc3;
      *ac = __builtin_amdgcn_mfma_f32_16x16x32_bf16(af0, b0, *ac, 0, 0, 0);
      *ac = __builtin_amdgcn_mfma_f32_16x16x32_bf16(af1, b1, *ac, 0, 0, 0);
    }
  };

  STAGE(0, 0);
  asm volatile("s_waitcnt vmcnt(0)" ::: "memory");
  __builtin_amdgcn_s_barrier();
  int cur = 0;
  for (int t = 0; t < NSTEP - 1; ++t) {
    STAGE(cur ^ 1, t + 1);
    COMPUTE(cur);
    asm volatile("s_waitcnt vmcnt(0)" ::: "memory");
    __builtin_amdgcn_s_barrier();
    cur ^= 1;
  }
  COMPUTE(cur);

  float* pp = partial + (size_t)ks * OUTTOT;
  int colb = nh * 64 + lr;
#pragma unroll
  for (int j = 0; j < 4; ++j) {
    int m = mt * 32 + mh * 16 + g * 4 + j;
    if (m < NN) {
      pp[m * LL + colb]      = acc0[j];
      pp[m * LL + colb + 16] = acc1[j];
      pp[m * LL + colb + 32] = acc2[j];
      pp[m * LL + colb + 48] = acc3[j];
    }
  }
}

// ---- K_red: reduce 32 partials (float4), add LPb to cols 64..127
__global__ __launch_bounds__(256) void k_red(const float* __restrict__ partial,
                                             const float* __restrict__ LPb,
                                             float* __restrict__ hcat) {
  int i4 = blockIdx.x * 256 + threadIdx.x;
  if (i4 * 4 >= OUTTOT) return;
  f32x4 s = {0.f, 0.f, 0.f, 0.f};
#pragma unroll
  for (int ks = 0; ks < KSPLIT; ++ks)
    s += *reinterpret_cast<const f32x4*>(partial + (size_t)ks * OUTTOT + i4 * 4);
  int n = (i4 * 4) & 127;
  if (n & 64) s += *reinterpret_cast<const f32x4*>(LPb + (n - 64));
  *reinterpret_cast<f32x4*>(hcat + i4 * 4) = s;
}

// ---- K_aggsilu: GCN1 gather + residual + bias + self-loop + SiLU + LN stats
__global__ __launch_bounds__(256) void k_aggsilu(const int* __restrict__ offs,
                                                 const int* __restrict__ srcs,
                                                 const float* __restrict__ dinv,
                                                 const float* __restrict__ hcat,
                                                 const float* __restrict__ b1,
                                                 float* __restrict__ hn,
                                                 float* __restrict__ stats) {
  int c = blockIdx.x;
  int j = threadIdx.x & 63, qt = threadIdx.x >> 6;
  int o0 = offs[c], o1 = offs[c + 1];
  float acc = 0.f;
  for (int i = o0 + qt; i < o1; i += 4) {
    int r = srcs[i];
    acc += hcat[r * LL + j] * dinv[r];
  }
  __shared__ float red[4][64];
  red[qt][j] = acc;
  __syncthreads();
  if (qt == 0) {
    float di = dinv[c];
    float gb = (red[0][j] + red[1][j] + red[2][j] + red[3][j]) * di;
    float t = hcat[c * LL + 64 + j] + b1[j] + gb + hcat[c * LL + j] * di * di;
    float s = t / (1.f + __expf(-t));
    hn[c * HH + j] = s;
    float sum = s, sq = s * s;
#pragma unroll
    for (int o = 32; o; o >>= 1) { sum += __shfl_down(sum, o); sq += __shfl_down(sq, o); }
    if (j == 0) { atomicAdd(&stats[0], sum); atomicAdd(&stats[1], sq); }
  }
}

// ---- K_ng2: normalize row + (hn@W2)*dinv
__global__ __launch_bounds__(128) void k_ng2(const float* __restrict__ hn,
                                             const float* __restrict__ stats,
                                             const float* __restrict__ W2,
                                             const float* __restrict__ dinv,
                                             float* __restrict__ hw) {
  int i = blockIdx.x;
  int j = threadIdx.x;
  __shared__ float hnl[64];
  float mu = stats[0] * (1.f / TOT);
  float var = stats[1] * (1.f / TOT) - mu * mu;
  float rs = rsqrtf(var + 1e-5f);
  if (j < 64) hnl[j] = (hn[i * HH + j] - mu) * rs;
  __syncthreads();
  float acc = 0.f;
#pragma unroll
  for (int k = 0; k < HH; ++k) acc += hnl[k] * W2[k * LL + j];
  hw[i * LL + j] = acc * dinv[i];
}

// ---- K_agg2: GCN2 gather + bias + self loop
__global__ __launch_bounds__(256) void k_agg2(const int* __restrict__ offs,
                                              const int* __restrict__ srcs,
                                              const float* __restrict__ dinv,
                                              const float* __restrict__ hw,
                                              const float* __restrict__ b2,
                                              float* __restrict__ out) {
  int c = blockIdx.x;
  int j = threadIdx.x & 127, hf = threadIdx.x >> 7;
  int o0 = offs[c], o1 = offs[c + 1];
  float acc = 0.f;
  for (int i = o0 + hf; i < o1; i += 2) acc += hw[srcs[i] * LL + j];
  __shared__ float red[2][128];
  red[hf][j] = acc;
  __syncthreads();
  if (hf == 0)
    out[c * LL + j] = b2[j] + dinv[c] * (red[0][j] + red[1][j] + hw[c * LL + j]);
}

extern "C" void kernel_launch(void* const* d_in, const int* in_sizes, int n_in,
                              void* d_out, int out_size, void* d_ws, size_t ws_size,
                              hipStream_t stream) {
  const float* x   = (const float*)d_in[0];
  const int*   e32 = (const int*)d_in[1];
  const float* W1  = (const float*)d_in[2];
  const float* b1  = (const float*)d_in[3];
  const float* W2  = (const float*)d_in[4];
  const float* b2  = (const float*)d_in[5];
  const float* LPw = (const float*)d_in[6];
  const float* LPb = (const float*)d_in[7];
  int E = in_sizes[1] / 2;
  float* out = (float*)d_out;

  char* ws = (char*)d_ws;
  size_t wt_b   = (size_t)128 * WT_STRIDE * 2;   // 8,396,800
  size_t part_b = (size_t)KSPLIT * OUTTOT * 4;   // 10,584,064

  size_t o_partial = wt_b;
  size_t o_hn   = o_partial;                 // aliases partial (dead after k_red)
  size_t o_hw   = o_hn + 165376;
  size_t o_hcat = o_partial + part_b;
  size_t o_dinv = o_hcat + 330752;
  size_t o_offs = o_dinv + 2816;
  size_t o_cnt  = o_offs + 2816;             // cnt[646] + stats[2], zeroed together
  size_t o_stat = o_cnt + 2592;
  size_t o_cur  = o_cnt + 2816;
  size_t o_srcs = o_cur + 2816;

  unsigned short* wt = (unsigned short*)ws;
  float* partial = (float*)(ws + o_partial);
  float* hn      = (float*)(ws + o_hn);
  float* hw      = (float*)(ws + o_hw);
  float* hcat    = (float*)(ws + o_hcat);
  float* dinv    = (float*)(ws + o_dinv);
  int*   offs    = (int*)(ws + o_offs);
  int*   cnt     = (int*)(ws + o_cnt);
  float* stats   = (float*)(ws + o_stat);
  int*   cursor  = (int*)(ws + o_cur);
  int*   srcs    = (int*)(ws + o_srcs);

  hipMemsetAsync(ws + o_cnt, 0, 2600, stream);
  k_init<<<576, 256, 0, stream>>>(W1, LPw, wt, e32, E, cnt);
  k_scan<<<1, 1024, 0, stream>>>(cnt, E, offs, dinv, cursor);
  k_place<<<(E + 255) / 256, 256, 0, stream>>>(e32, E, cursor, srcs);
  k_gemm<<<21 * KSPLIT, 256, 0, stream>>>(x, wt, partial);
  k_red<<<(OUTTOT / 4 + 255) / 256, 256, 0, stream>>>(partial, LPb, hcat);
  k_aggsilu<<<NN, 256, 0, stream>>>(offs, srcs, dinv, hcat, b1, hn, stats);
  k_ng2<<<NN, 128, 0, stream>>>(hn, stats, W2, dinv, hw);
  k_agg2<<<NN, 256, 0, stream>>>(offs, srcs, dinv, hw, b2, out);
}

// Round 6
// 97.556 us; speedup vs baseline: 1.7760x; 1.0836x over previous
//
#include <hip/hip_runtime.h>
#include <hip/hip_bf16.h>

#define NN 646
#define FF 32768
#define HH 64
#define LL 128
#define TOT (NN*HH)          // 41344
#define OUTTOT (NN*LL)       // 82688
#define WT_STRIDE (FF + 32)  // padded bf16 row
#define KSPLIT 32
#define KSLICE (FF / KSPLIT) // 1024
#define NSTEP (KSLICE / 64)  // 16

typedef float f32x4 __attribute__((ext_vector_type(4)));
typedef short short8 __attribute__((ext_vector_type(8)));

__device__ __forceinline__ unsigned short f2bf(float f) {
  __hip_bfloat16 h = __float2bfloat16(f);
  return __builtin_bit_cast(unsigned short, h);
}
__device__ __forceinline__ short8 pack8(float4 u, float4 v) {
  short8 r;
  r[0] = (short)f2bf(u.x); r[1] = (short)f2bf(u.y);
  r[2] = (short)f2bf(u.z); r[3] = (short)f2bf(u.w);
  r[4] = (short)f2bf(v.x); r[5] = (short)f2bf(v.y);
  r[6] = (short)f2bf(v.z); r[7] = (short)f2bf(v.w);
  return r;
}
__device__ __forceinline__ void gload16(const void* g, void* l) {
  __builtin_amdgcn_global_load_lds(
      (const __attribute__((address_space(1))) void*)g,
      (__attribute__((address_space(3))) void*)l, 16, 0, 0);
}
// block-level edge-dtype probe: true if int64 (all sampled hi-words zero)
__device__ __forceinline__ bool probe_i64(const int* e32, int* orr) {
  if (threadIdx.x == 0) *orr = 0;
  __syncthreads();
  if (threadIdx.x < 256 && e32[2 * threadIdx.x + 1] != 0) atomicOr(orr, 1);
  __syncthreads();
  return *orr == 0;
}

// ---- K_init: blocks 0..511 transpose [W1|LPw] -> wt (16B stores);
//      blocks 512..575 count degrees; block 576 = W2 column sums
__global__ __launch_bounds__(256) void k_init(const float* __restrict__ W1,
                                              const float* __restrict__ LPw,
                                              unsigned short* __restrict__ wt,
                                              const int* __restrict__ e32, int E,
                                              int* __restrict__ cnt,
                                              const float* __restrict__ W2,
                                              float* __restrict__ cs) {
  if (blockIdx.x < 512) {
    __shared__ float t[64][129];
    int k0 = blockIdx.x * 64;
    for (int idx = threadIdx.x; idx < 64 * 128; idx += 256) {
      int kk = idx >> 7, n = idx & 127;
      float v = (n < 64) ? W1[(size_t)(k0 + kk) * 64 + n]
                         : LPw[(size_t)(k0 + kk) * 64 + (n - 64)];
      t[kk][n] = v;
    }
    __syncthreads();
    // 16B vectorized stores: 1024 chunks of 8 bf16
    for (int idx = threadIdx.x; idx < 1024; idx += 256) {
      int n = idx >> 3;
      int kc = (idx & 7) * 8;
      short8 v;
#pragma unroll
      for (int u = 0; u < 8; ++u) v[u] = (short)f2bf(t[kc + u][n]);
      *reinterpret_cast<short8*>(&wt[(size_t)n * WT_STRIDE + k0 + kc]) = v;
    }
    return;
  }
  if (blockIdx.x == 576) {  // cs[j] = sum_k W2[k][j]
    __shared__ float r2[2][128];
    int j = threadIdx.x & 127, h = threadIdx.x >> 7;
    float a = 0.f;
    for (int k = h * 32; k < h * 32 + 32; ++k) a += W2[k * LL + j];
    r2[h][j] = a;
    __syncthreads();
    if (h == 0) cs[j] = r2[0][j] + r2[1][j];
    return;
  }
  __shared__ int orr;
  bool i64 = probe_i64(e32, &orr);
  const int* cp = i64 ? (e32 + 2 * (size_t)E) : (e32 + E);
  int st = i64 ? 2 : 1;
  int wid = (blockIdx.x - 512) * 256 + threadIdx.x;
  for (int e = wid; e < E; e += 64 * 256)
    atomicAdd(&cnt[cp[(size_t)e * st]], 1);
}

// ---- K_gemm: counted-vmcnt 2-deep global_load_lds pipeline (T3+T4);
//      block 672 does the CSR scan instead
__global__ __launch_bounds__(256, 3) void k_gemm(const float* __restrict__ x,
                                                 const unsigned short* __restrict__ wt,
                                                 float* __restrict__ partial,
                                                 const int* __restrict__ cnt, int E,
                                                 int* __restrict__ offsets,
                                                 float* __restrict__ dinv,
                                                 int* __restrict__ cursor) {
  __shared__ __align__(16) float As[2][32 * 64];            // 16 KB
  __shared__ __align__(16) unsigned short Bs[2][128 * 64];  // 32 KB

  int p = blockIdx.x;
  if (p == 672) {  // ---- scan block: offsets/dinv/cursor from cnt
    __shared__ int wtot[4];
    int tid = threadIdx.x;
    int b = 3 * tid;
    int c0 = (b < NN) ? cnt[b] : 0;
    int c1 = (b + 1 < NN) ? cnt[b + 1] : 0;
    int c2 = (b + 2 < NN) ? cnt[b + 2] : 0;
    int s = c0 + c1 + c2;
    int lane = tid & 63, wv = tid >> 6;
    int run = s;
#pragma unroll
    for (int o = 1; o < 64; o <<= 1) { int v = __shfl_up(run, o); if (lane >= o) run += v; }
    if (lane == 63) wtot[wv] = run;
    __syncthreads();
    int wbase = 0;
    for (int i = 0; i < wv; ++i) wbase += wtot[i];
    int excl = wbase + run - s;
    if (b < NN)     { offsets[b]     = excl;           cursor[b]     = excl;           dinv[b]     = rsqrtf((float)(c0 + 1)); }
    if (b + 1 < NN) { offsets[b + 1] = excl + c0;      cursor[b + 1] = excl + c0;      dinv[b + 1] = rsqrtf((float)(c1 + 1)); }
    if (b + 2 < NN) { offsets[b + 2] = excl + c0 + c1; cursor[b + 2] = excl + c0 + c1; dinv[b + 2] = rsqrtf((float)(c2 + 1)); }
    if (tid == 0) offsets[NN] = E;
    return;
  }

  int xcd = p & 7, idx = p >> 3;       // 672 = 8 * 84, 84 = 4*21
  int ks = xcd + 8 * (idx / 21);       // same-ks blocks share an XCD's L2
  int mt = idx % 21;
  int tid = threadIdx.x;
  int w = tid >> 6, l = tid & 63;
  int lr = l & 15, g = l >> 4;
  int mh = w & 1, nh = w >> 1;
  int ksbase = ks * KSLICE;

  f32x4 acc0 = {0.f, 0.f, 0.f, 0.f}, acc1 = acc0, acc2 = acc0, acc3 = acc0;
  int arow = mh * 16 + lr, arm = arow & 7;

  auto STAGE = [&](int buf, int step) {
    int kb = ksbase + step * 64;
#pragma unroll
    for (int j = 0; j < 2; ++j) {
      int pp = j * 256 + tid;
      int row = pp >> 4, cc = pp & 15;
      int c = cc ^ (row & 7);
      int rowg = mt * 32 + row; if (rowg > NN - 1) rowg = NN - 1;
      gload16(x + (size_t)rowg * FF + kb + c * 4, (char*)(&As[buf][0]) + pp * 16);
    }
#pragma unroll
    for (int j = 0; j < 4; ++j) {
      int pp = j * 256 + tid;
      int row = pp >> 3, cc = pp & 7;
      int c = cc ^ (row & 7);
      gload16(wt + (size_t)row * WT_STRIDE + kb + c * 8, (char*)(&Bs[buf][0]) + pp * 16);
    }
  };

  auto COMPUTE = [&](int buf) {
    const char* Ab = (const char*)(&As[buf][0]);
    const char* Bb = (const char*)(&Bs[buf][0]);
    int c0 = g * 2, c1 = 8 + g * 2;
    float4 lo0 = *(const float4*)(Ab + (arow * 16 + (c0 ^ arm)) * 16);
    float4 hi0 = *(const float4*)(Ab + (arow * 16 + ((c0 + 1) ^ arm)) * 16);
    float4 lo1 = *(const float4*)(Ab + (arow * 16 + (c1 ^ arm)) * 16);
    float4 hi1 = *(const float4*)(Ab + (arow * 16 + ((c1 + 1) ^ arm)) * 16);
    short8 af0 = pack8(lo0, hi0);
    short8 af1 = pack8(lo1, hi1);
#pragma unroll
    for (int nf = 0; nf < 4; ++nf) {
      int brow = nh * 64 + nf * 16 + lr;
      int brm = brow & 7;
      short8 b0 = *(const short8*)(Bb + (brow * 8 + (g ^ brm)) * 16);
      short8 b1 = *(const short8*)(Bb + (brow * 8 + ((4 + g) ^ brm)) * 16);
      f32x4* ac = (nf == 0) ? &acc0 : (nf == 1) ? &acc1 : (nf == 2) ? &acc2 : &acc3;
      *ac = __builtin_amdgcn_mfma_f32_16x16x32_bf16(af0, b0, *ac, 0, 0, 0);
      *ac = __builtin_amdgcn_mfma_f32_16x16x32_bf16(af1, b1, *ac, 0, 0, 0);
    }
  };

  STAGE(0, 0);
  STAGE(1, 1);
#pragma unroll
  for (int t = 0; t < NSTEP; ++t) {
    if (t + 1 < NSTEP) {
      asm volatile("s_waitcnt vmcnt(6)" ::: "memory");  // tile t done, tile t+1 in flight
    } else {
      asm volatile("s_waitcnt vmcnt(0)" ::: "memory");
    }
    __builtin_amdgcn_s_barrier();
    COMPUTE(t & 1);
    if (t + 2 < NSTEP) {
      __builtin_amdgcn_s_barrier();    // all waves done reading buf before overwrite
      STAGE(t & 1, t + 2);
    }
  }

  float* pp = partial + (size_t)ks * OUTTOT;
  int colb = nh * 64 + lr;
#pragma unroll
  for (int j = 0; j < 4; ++j) {
    int m = mt * 32 + mh * 16 + g * 4 + j;
    if (m < NN) {
      pp[m * LL + colb]      = acc0[j];
      pp[m * LL + colb + 16] = acc1[j];
      pp[m * LL + colb + 32] = acc2[j];
      pp[m * LL + colb + 48] = acc3[j];
    }
  }
}

// ---- K_redplace: blocks 0..80 reduce partials; blocks 81..242 CSR placement
__global__ __launch_bounds__(256) void k_redplace(const float* __restrict__ partial,
                                                  const float* __restrict__ LPb,
                                                  float* __restrict__ hcat,
                                                  const int* __restrict__ e32, int E,
                                                  int* __restrict__ cursor,
                                                  int* __restrict__ srcs) {
  if (blockIdx.x < 81) {
    int i4 = blockIdx.x * 256 + threadIdx.x;
    if (i4 * 4 >= OUTTOT) return;
    f32x4 s = {0.f, 0.f, 0.f, 0.f};
#pragma unroll
    for (int ks = 0; ks < KSPLIT; ++ks)
      s += *reinterpret_cast<const f32x4*>(partial + (size_t)ks * OUTTOT + i4 * 4);
    int n = (i4 * 4) & 127;
    if (n & 64) s += *reinterpret_cast<const f32x4*>(LPb + (n - 64));
    *reinterpret_cast<f32x4*>(hcat + i4 * 4) = s;
    return;
  }
  __shared__ int orr;
  bool i64 = probe_i64(e32, &orr);
  int e = (blockIdx.x - 81) * 256 + threadIdx.x;
  if (e >= E) return;
  const int* rp = e32;
  const int* cp = i64 ? (e32 + 2 * (size_t)E) : (e32 + E);
  int st = i64 ? 2 : 1;
  int r = rp[(size_t)e * st];
  int c = cp[(size_t)e * st];
  int pos = atomicAdd(&cursor[c], 1);
  srcs[pos] = r;
}

// ---- K_fuse1: GCN1 gather + residual + bias + self-loop + SiLU + LN stats
//      + sdi[c] + hwr[c] = (s_c @ W2) * dinv[c]   (LN folded out algebraically)
__global__ __launch_bounds__(256) void k_fuse1(const int* __restrict__ offs,
                                               const int* __restrict__ srcs,
                                               const float* __restrict__ dinv,
                                               const float* __restrict__ hcat,
                                               const float* __restrict__ b1,
                                               const float* __restrict__ W2,
                                               float* __restrict__ hwr,
                                               float* __restrict__ sdi,
                                               float* __restrict__ stats) {
  int c = blockIdx.x;
  int j = threadIdx.x & 63, qt = threadIdx.x >> 6;
  int o0 = offs[c], o1 = offs[c + 1];
  float acc = 0.f, sd = 0.f;
  for (int i = o0 + qt; i < o1; i += 4) {
    int r = srcs[i];
    float dr = dinv[r];
    acc += hcat[r * LL + j] * dr;
    sd += dr;
  }
  __shared__ float red[4][64];
  __shared__ float sdl[4];
  __shared__ float hnl[64];
  red[qt][j] = acc;
  if (j == 0) sdl[qt] = sd;
  __syncthreads();
  if (qt == 0) {
    float di = dinv[c];
    float gb = (red[0][j] + red[1][j] + red[2][j] + red[3][j]) * di;
    float t = hcat[c * LL + 64 + j] + b1[j] + gb + hcat[c * LL + j] * di * di;
    float s = t / (1.f + __expf(-t));
    hnl[j] = s;
    float sum = s, sq = s * s;
#pragma unroll
    for (int o = 32; o; o >>= 1) { sum += __shfl_down(sum, o); sq += __shfl_down(sq, o); }
    if (j == 0) {
      atomicAdd(&stats[0], sum);
      atomicAdd(&stats[1], sq);
      sdi[c] = sdl[0] + sdl[1] + sdl[2] + sdl[3] + di;
    }
  }
  __syncthreads();
  int j2 = threadIdx.x & 127, h = threadIdx.x >> 7;
  float a2 = 0.f;
#pragma unroll
  for (int k = h * 32; k < h * 32 + 32; ++k) a2 += hnl[k] * W2[k * LL + j2];
  __shared__ float r2[2][128];
  r2[h][j2] = a2;
  __syncthreads();
  if (h == 0) hwr[c * LL + j2] = (r2[0][j2] + r2[1][j2]) * dinv[c];
}

// ---- K_fuse2: GCN2 gather + LN constants + bias + self loop
//      out[c][j] = b2[j] + dinv[c]*( rs*(sum_r hwr[r][j] + hwr[c][j]) - rs*mu*cs[j]*sdi[c] )
__global__ __launch_bounds__(256) void k_fuse2(const int* __restrict__ offs,
                                               const int* __restrict__ srcs,
                                               const float* __restrict__ dinv,
                                               const float* __restrict__ hwr,
                                               const float* __restrict__ b2,
                                               const float* __restrict__ cs,
                                               const float* __restrict__ sdi,
                                               const float* __restrict__ stats,
                                               float* __restrict__ out) {
  int c = blockIdx.x;
  int j = threadIdx.x & 127, hf = threadIdx.x >> 7;
  int o0 = offs[c], o1 = offs[c + 1];
  float acc = 0.f;
  for (int i = o0 + hf; i < o1; i += 2) acc += hwr[srcs[i] * LL + j];
  __shared__ float red[2][128];
  red[hf][j] = acc;
  __syncthreads();
  if (hf == 0) {
    float mu = stats[0] * (1.f / TOT);
    float var = stats[1] * (1.f / TOT) - mu * mu;
    float rs = rsqrtf(var + 1e-5f);
    float S = red[0][j] + red[1][j] + hwr[c * LL + j];
    out[c * LL + j] = b2[j] + dinv[c] * (rs * S - rs * mu * cs[j] * sdi[c]);
  }
}

extern "C" void kernel_launch(void* const* d_in, const int* in_sizes, int n_in,
                              void* d_out, int out_size, void* d_ws, size_t ws_size,
                              hipStream_t stream) {
  const float* x   = (const float*)d_in[0];
  const int*   e32 = (const int*)d_in[1];
  const float* W1  = (const float*)d_in[2];
  const float* b1  = (const float*)d_in[3];
  const float* W2  = (const float*)d_in[4];
  const float* b2  = (const float*)d_in[5];
  const float* LPw = (const float*)d_in[6];
  const float* LPb = (const float*)d_in[7];
  int E = in_sizes[1] / 2;
  float* out = (float*)d_out;

  char* ws = (char*)d_ws;
  size_t o_wt      = 0;
  size_t o_partial = 8396800;                       // 128*WT_STRIDE*2
  size_t o_hcat    = o_partial + (size_t)KSPLIT * OUTTOT * 4;   // +10,584,064
  size_t o_hwr     = o_hcat + 330752;
  size_t o_dinv    = o_hwr + 330752;
  size_t o_offs    = o_dinv + 2816;
  size_t o_cnt     = o_offs + 2816;
  size_t o_stat    = o_cnt + 2592;                  // memset covers cnt+stats (2600 B)
  size_t o_cur     = o_cnt + 2816;
  size_t o_srcs    = o_cur + 2816;
  size_t o_cs      = o_srcs + 165376;
  size_t o_sdi     = o_cs + 512;

  unsigned short* wt = (unsigned short*)(ws + o_wt);
  float* partial = (float*)(ws + o_partial);
  float* hcat    = (float*)(ws + o_hcat);
  float* hwr     = (float*)(ws + o_hwr);
  float* dinv    = (float*)(ws + o_dinv);
  int*   offs    = (int*)(ws + o_offs);
  int*   cnt     = (int*)(ws + o_cnt);
  float* stats   = (float*)(ws + o_stat);
  int*   cursor  = (int*)(ws + o_cur);
  int*   srcs    = (int*)(ws + o_srcs);
  float* cs      = (float*)(ws + o_cs);
  float* sdi     = (float*)(ws + o_sdi);

  hipMemsetAsync(ws + o_cnt, 0, 2600, stream);
  k_init<<<577, 256, 0, stream>>>(W1, LPw, wt, e32, E, cnt, W2, cs);
  k_gemm<<<673, 256, 0, stream>>>(x, wt, partial, cnt, E, offs, dinv, cursor);
  k_redplace<<<243, 256, 0, stream>>>(partial, LPb, hcat, e32, E, cursor, srcs);
  k_fuse1<<<NN, 256, 0, stream>>>(offs, srcs, dinv, hcat, b1, W2, hwr, sdi, stats);
  k_fuse2<<<NN, 256, 0, stream>>>(offs, srcs, dinv, hwr, b2, cs, sdi, stats, out);
}

// Round 7
// 94.906 us; speedup vs baseline: 1.8256x; 1.0279x over previous
//
#include <hip/hip_runtime.h>
#include <hip/hip_bf16.h>

#define NN 646
#define FF 32768
#define HH 64
#define LL 128
#define TOT (NN*HH)          // 41344
#define OUTTOT (NN*LL)       // 82688
#define WT_STRIDE (FF + 32)  // padded bf16 row
#define KSPLIT 32
#define KSLICE (FF / KSPLIT) // 1024
#define NSTEP (KSLICE / 64)  // 16

typedef float f32x4 __attribute__((ext_vector_type(4)));
typedef short short8 __attribute__((ext_vector_type(8)));

__device__ __forceinline__ unsigned short f2bf(float f) {
  __hip_bfloat16 h = __float2bfloat16(f);
  return __builtin_bit_cast(unsigned short, h);
}
__device__ __forceinline__ short8 pack8(float4 u, float4 v) {
  short8 r;
  r[0] = (short)f2bf(u.x); r[1] = (short)f2bf(u.y);
  r[2] = (short)f2bf(u.z); r[3] = (short)f2bf(u.w);
  r[4] = (short)f2bf(v.x); r[5] = (short)f2bf(v.y);
  r[6] = (short)f2bf(v.z); r[7] = (short)f2bf(v.w);
  return r;
}
__device__ __forceinline__ void gload16(const void* g, void* l) {
  __builtin_amdgcn_global_load_lds(
      (const __attribute__((address_space(1))) void*)g,
      (__attribute__((address_space(3))) void*)l, 16, 0, 0);
}
// block-level edge-dtype probe: true if int64 (all sampled hi-words zero)
__device__ __forceinline__ bool probe_i64(const int* e32, int* orr) {
  if (threadIdx.x == 0) *orr = 0;
  __syncthreads();
  if (threadIdx.x < 256 && e32[2 * threadIdx.x + 1] != 0) atomicOr(orr, 1);
  __syncthreads();
  return *orr == 0;
}

// ---- K_zero: replaces hipMemsetAsync (fillBufferAligned was ~48us/call)
__global__ __launch_bounds__(1024) void k_zero(int* __restrict__ cnt,
                                               float* __restrict__ stats) {
  int t = threadIdx.x;
  if (t < NN) cnt[t] = 0;
  if (t < 2) stats[t] = 0.f;
}

// ---- K_init: blocks 0..511 transpose [W1|LPw] -> wt (16B stores);
//      blocks 512..575 count degrees; block 576 = W2 column sums
__global__ __launch_bounds__(256) void k_init(const float* __restrict__ W1,
                                              const float* __restrict__ LPw,
                                              unsigned short* __restrict__ wt,
                                              const int* __restrict__ e32, int E,
                                              int* __restrict__ cnt,
                                              const float* __restrict__ W2,
                                              float* __restrict__ cs) {
  if (blockIdx.x < 512) {
    __shared__ float t[64][129];
    int k0 = blockIdx.x * 64;
    for (int idx = threadIdx.x; idx < 64 * 128; idx += 256) {
      int kk = idx >> 7, n = idx & 127;
      float v = (n < 64) ? W1[(size_t)(k0 + kk) * 64 + n]
                         : LPw[(size_t)(k0 + kk) * 64 + (n - 64)];
      t[kk][n] = v;
    }
    __syncthreads();
    // 16B vectorized stores: 1024 chunks of 8 bf16
    for (int idx = threadIdx.x; idx < 1024; idx += 256) {
      int n = idx >> 3;
      int kc = (idx & 7) * 8;
      short8 v;
#pragma unroll
      for (int u = 0; u < 8; ++u) v[u] = (short)f2bf(t[kc + u][n]);
      *reinterpret_cast<short8*>(&wt[(size_t)n * WT_STRIDE + k0 + kc]) = v;
    }
    return;
  }
  if (blockIdx.x == 576) {  // cs[j] = sum_k W2[k][j]
    __shared__ float r2[2][128];
    int j = threadIdx.x & 127, h = threadIdx.x >> 7;
    float a = 0.f;
    for (int k = h * 32; k < h * 32 + 32; ++k) a += W2[k * LL + j];
    r2[h][j] = a;
    __syncthreads();
    if (h == 0) cs[j] = r2[0][j] + r2[1][j];
    return;
  }
  __shared__ int orr;
  bool i64 = probe_i64(e32, &orr);
  const int* cp = i64 ? (e32 + 2 * (size_t)E) : (e32 + E);
  int st = i64 ? 2 : 1;
  int wid = (blockIdx.x - 512) * 256 + threadIdx.x;
  for (int e = wid; e < E; e += 64 * 256)
    atomicAdd(&cnt[cp[(size_t)e * st]], 1);
}

// ---- K_gemm: counted-vmcnt 2-deep global_load_lds pipeline (T3+T4);
//      block 672 does the CSR scan instead
__global__ __launch_bounds__(256, 3) void k_gemm(const float* __restrict__ x,
                                                 const unsigned short* __restrict__ wt,
                                                 float* __restrict__ partial,
                                                 const int* __restrict__ cnt, int E,
                                                 int* __restrict__ offsets,
                                                 float* __restrict__ dinv,
                                                 int* __restrict__ cursor) {
  __shared__ __align__(16) float As[2][32 * 64];            // 16 KB
  __shared__ __align__(16) unsigned short Bs[2][128 * 64];  // 32 KB

  int p = blockIdx.x;
  if (p == 672) {  // ---- scan block: offsets/dinv/cursor from cnt
    __shared__ int wtot[4];
    int tid = threadIdx.x;
    int b = 3 * tid;
    int c0 = (b < NN) ? cnt[b] : 0;
    int c1 = (b + 1 < NN) ? cnt[b + 1] : 0;
    int c2 = (b + 2 < NN) ? cnt[b + 2] : 0;
    int s = c0 + c1 + c2;
    int lane = tid & 63, wv = tid >> 6;
    int run = s;
#pragma unroll
    for (int o = 1; o < 64; o <<= 1) { int v = __shfl_up(run, o); if (lane >= o) run += v; }
    if (lane == 63) wtot[wv] = run;
    __syncthreads();
    int wbase = 0;
    for (int i = 0; i < wv; ++i) wbase += wtot[i];
    int excl = wbase + run - s;
    if (b < NN)     { offsets[b]     = excl;           cursor[b]     = excl;           dinv[b]     = rsqrtf((float)(c0 + 1)); }
    if (b + 1 < NN) { offsets[b + 1] = excl + c0;      cursor[b + 1] = excl + c0;      dinv[b + 1] = rsqrtf((float)(c1 + 1)); }
    if (b + 2 < NN) { offsets[b + 2] = excl + c0 + c1; cursor[b + 2] = excl + c0 + c1; dinv[b + 2] = rsqrtf((float)(c2 + 1)); }
    if (tid == 0) offsets[NN] = E;
    return;
  }

  int xcd = p & 7, idx = p >> 3;       // 672 = 8 * 84, 84 = 4*21
  int ks = xcd + 8 * (idx / 21);       // same-ks blocks share an XCD's L2
  int mt = idx % 21;
  int tid = threadIdx.x;
  int w = tid >> 6, l = tid & 63;
  int lr = l & 15, g = l >> 4;
  int mh = w & 1, nh = w >> 1;
  int ksbase = ks * KSLICE;

  f32x4 acc0 = {0.f, 0.f, 0.f, 0.f}, acc1 = acc0, acc2 = acc0, acc3 = acc0;
  int arow = mh * 16 + lr, arm = arow & 7;

  auto STAGE = [&](int buf, int step) {
    int kb = ksbase + step * 64;
#pragma unroll
    for (int j = 0; j < 2; ++j) {
      int pp = j * 256 + tid;
      int row = pp >> 4, cc = pp & 15;
      int c = cc ^ (row & 7);
      int rowg = mt * 32 + row; if (rowg > NN - 1) rowg = NN - 1;
      gload16(x + (size_t)rowg * FF + kb + c * 4, (char*)(&As[buf][0]) + pp * 16);
    }
#pragma unroll
    for (int j = 0; j < 4; ++j) {
      int pp = j * 256 + tid;
      int row = pp >> 3, cc = pp & 7;
      int c = cc ^ (row & 7);
      gload16(wt + (size_t)row * WT_STRIDE + kb + c * 8, (char*)(&Bs[buf][0]) + pp * 16);
    }
  };

  auto COMPUTE = [&](int buf) {
    const char* Ab = (const char*)(&As[buf][0]);
    const char* Bb = (const char*)(&Bs[buf][0]);
    int c0 = g * 2, c1 = 8 + g * 2;
    float4 lo0 = *(const float4*)(Ab + (arow * 16 + (c0 ^ arm)) * 16);
    float4 hi0 = *(const float4*)(Ab + (arow * 16 + ((c0 + 1) ^ arm)) * 16);
    float4 lo1 = *(const float4*)(Ab + (arow * 16 + (c1 ^ arm)) * 16);
    float4 hi1 = *(const float4*)(Ab + (arow * 16 + ((c1 + 1) ^ arm)) * 16);
    short8 af0 = pack8(lo0, hi0);
    short8 af1 = pack8(lo1, hi1);
#pragma unroll
    for (int nf = 0; nf < 4; ++nf) {
      int brow = nh * 64 + nf * 16 + lr;
      int brm = brow & 7;
      short8 b0 = *(const short8*)(Bb + (brow * 8 + (g ^ brm)) * 16);
      short8 b1 = *(const short8*)(Bb + (brow * 8 + ((4 + g) ^ brm)) * 16);
      f32x4* ac = (nf == 0) ? &acc0 : (nf == 1) ? &acc1 : (nf == 2) ? &acc2 : &acc3;
      *ac = __builtin_amdgcn_mfma_f32_16x16x32_bf16(af0, b0, *ac, 0, 0, 0);
      *ac = __builtin_amdgcn_mfma_f32_16x16x32_bf16(af1, b1, *ac, 0, 0, 0);
    }
  };

  STAGE(0, 0);
  STAGE(1, 1);
#pragma unroll
  for (int t = 0; t < NSTEP; ++t) {
    if (t + 1 < NSTEP) {
      asm volatile("s_waitcnt vmcnt(6)" ::: "memory");  // tile t done, tile t+1 in flight
    } else {
      asm volatile("s_waitcnt vmcnt(0)" ::: "memory");
    }
    __builtin_amdgcn_s_barrier();
    COMPUTE(t & 1);
    if (t + 2 < NSTEP) {
      __builtin_amdgcn_s_barrier();    // all waves done reading buf before overwrite
      STAGE(t & 1, t + 2);
    }
  }

  float* pp = partial + (size_t)ks * OUTTOT;
  int colb = nh * 64 + lr;
#pragma unroll
  for (int j = 0; j < 4; ++j) {
    int m = mt * 32 + mh * 16 + g * 4 + j;
    if (m < NN) {
      pp[m * LL + colb]      = acc0[j];
      pp[m * LL + colb + 16] = acc1[j];
      pp[m * LL + colb + 32] = acc2[j];
      pp[m * LL + colb + 48] = acc3[j];
    }
  }
}

// ---- K_redplace: blocks 0..80 reduce partials; blocks 81..242 CSR placement
__global__ __launch_bounds__(256) void k_redplace(const float* __restrict__ partial,
                                                  const float* __restrict__ LPb,
                                                  float* __restrict__ hcat,
                                                  const int* __restrict__ e32, int E,
                                                  int* __restrict__ cursor,
                                                  int* __restrict__ srcs) {
  if (blockIdx.x < 81) {
    int i4 = blockIdx.x * 256 + threadIdx.x;
    if (i4 * 4 >= OUTTOT) return;
    f32x4 s = {0.f, 0.f, 0.f, 0.f};
#pragma unroll
    for (int ks = 0; ks < KSPLIT; ++ks)
      s += *reinterpret_cast<const f32x4*>(partial + (size_t)ks * OUTTOT + i4 * 4);
    int n = (i4 * 4) & 127;
    if (n & 64) s += *reinterpret_cast<const f32x4*>(LPb + (n - 64));
    *reinterpret_cast<f32x4*>(hcat + i4 * 4) = s;
    return;
  }
  __shared__ int orr;
  bool i64 = probe_i64(e32, &orr);
  int e = (blockIdx.x - 81) * 256 + threadIdx.x;
  if (e >= E) return;
  const int* rp = e32;
  const int* cp = i64 ? (e32 + 2 * (size_t)E) : (e32 + E);
  int st = i64 ? 2 : 1;
  int r = rp[(size_t)e * st];
  int c = cp[(size_t)e * st];
  int pos = atomicAdd(&cursor[c], 1);
  srcs[pos] = r;
}

// ---- K_fuse1: GCN1 gather + residual + bias + self-loop + SiLU + LN stats
//      + sdi[c] + hwr[c] = (s_c @ W2) * dinv[c]   (LN folded out algebraically)
__global__ __launch_bounds__(256) void k_fuse1(const int* __restrict__ offs,
                                               const int* __restrict__ srcs,
                                               const float* __restrict__ dinv,
                                               const float* __restrict__ hcat,
                                               const float* __restrict__ b1,
                                               const float* __restrict__ W2,
                                               float* __restrict__ hwr,
                                               float* __restrict__ sdi,
                                               float* __restrict__ stats) {
  int c = blockIdx.x;
  int j = threadIdx.x & 63, qt = threadIdx.x >> 6;
  int o0 = offs[c], o1 = offs[c + 1];
  float acc = 0.f, sd = 0.f;
  for (int i = o0 + qt; i < o1; i += 4) {
    int r = srcs[i];
    float dr = dinv[r];
    acc += hcat[r * LL + j] * dr;
    sd += dr;
  }
  __shared__ float red[4][64];
  __shared__ float sdl[4];
  __shared__ float hnl[64];
  red[qt][j] = acc;
  if (j == 0) sdl[qt] = sd;
  __syncthreads();
  if (qt == 0) {
    float di = dinv[c];
    float gb = (red[0][j] + red[1][j] + red[2][j] + red[3][j]) * di;
    float t = hcat[c * LL + 64 + j] + b1[j] + gb + hcat[c * LL + j] * di * di;
    float s = t / (1.f + __expf(-t));
    hnl[j] = s;
    float sum = s, sq = s * s;
#pragma unroll
    for (int o = 32; o; o >>= 1) { sum += __shfl_down(sum, o); sq += __shfl_down(sq, o); }
    if (j == 0) {
      atomicAdd(&stats[0], sum);
      atomicAdd(&stats[1], sq);
      sdi[c] = sdl[0] + sdl[1] + sdl[2] + sdl[3] + di;
    }
  }
  __syncthreads();
  int j2 = threadIdx.x & 127, h = threadIdx.x >> 7;
  float a2 = 0.f;
#pragma unroll
  for (int k = h * 32; k < h * 32 + 32; ++k) a2 += hnl[k] * W2[k * LL + j2];
  __shared__ float r2[2][128];
  r2[h][j2] = a2;
  __syncthreads();
  if (h == 0) hwr[c * LL + j2] = (r2[0][j2] + r2[1][j2]) * dinv[c];
}

// ---- K_fuse2: GCN2 gather + LN constants + bias + self loop
//      out[c][j] = b2[j] + dinv[c]*( rs*(sum_r hwr[r][j] + hwr[c][j]) - rs*mu*cs[j]*sdi[c] )
__global__ __launch_bounds__(256) void k_fuse2(const int* __restrict__ offs,
                                               const int* __restrict__ srcs,
                                               const float* __restrict__ dinv,
                                               const float* __restrict__ hwr,
                                               const float* __restrict__ b2,
                                               const float* __restrict__ cs,
                                               const float* __restrict__ sdi,
                                               const float* __restrict__ stats,
                                               float* __restrict__ out) {
  int c = blockIdx.x;
  int j = threadIdx.x & 127, hf = threadIdx.x >> 7;
  int o0 = offs[c], o1 = offs[c + 1];
  float acc = 0.f;
  for (int i = o0 + hf; i < o1; i += 2) acc += hwr[srcs[i] * LL + j];
  __shared__ float red[2][128];
  red[hf][j] = acc;
  __syncthreads();
  if (hf == 0) {
    float mu = stats[0] * (1.f / TOT);
    float var = stats[1] * (1.f / TOT) - mu * mu;
    float rs = rsqrtf(var + 1e-5f);
    float S = red[0][j] + red[1][j] + hwr[c * LL + j];
    out[c * LL + j] = b2[j] + dinv[c] * (rs * S - rs * mu * cs[j] * sdi[c]);
  }
}

extern "C" void kernel_launch(void* const* d_in, const int* in_sizes, int n_in,
                              void* d_out, int out_size, void* d_ws, size_t ws_size,
                              hipStream_t stream) {
  const float* x   = (const float*)d_in[0];
  const int*   e32 = (const int*)d_in[1];
  const float* W1  = (const float*)d_in[2];
  const float* b1  = (const float*)d_in[3];
  const float* W2  = (const float*)d_in[4];
  const float* b2  = (const float*)d_in[5];
  const float* LPw = (const float*)d_in[6];
  const float* LPb = (const float*)d_in[7];
  int E = in_sizes[1] / 2;
  float* out = (float*)d_out;

  char* ws = (char*)d_ws;
  size_t o_wt      = 0;
  size_t o_partial = 8396800;                       // 128*WT_STRIDE*2
  size_t o_hcat    = o_partial + (size_t)KSPLIT * OUTTOT * 4;   // +10,584,064
  size_t o_hwr     = o_hcat + 330752;
  size_t o_dinv    = o_hwr + 330752;
  size_t o_offs    = o_dinv + 2816;
  size_t o_cnt     = o_offs + 2816;
  size_t o_stat    = o_cnt + 2592;
  size_t o_cur     = o_cnt + 2816;
  size_t o_srcs    = o_cur + 2816;
  size_t o_cs      = o_srcs + 165376;
  size_t o_sdi     = o_cs + 512;

  unsigned short* wt = (unsigned short*)(ws + o_wt);
  float* partial = (float*)(ws + o_partial);
  float* hcat    = (float*)(ws + o_hcat);
  float* hwr     = (float*)(ws + o_hwr);
  float* dinv    = (float*)(ws + o_dinv);
  int*   offs    = (int*)(ws + o_offs);
  int*   cnt     = (int*)(ws + o_cnt);
  float* stats   = (float*)(ws + o_stat);
  int*   cursor  = (int*)(ws + o_cur);
  int*   srcs    = (int*)(ws + o_srcs);
  float* cs      = (float*)(ws + o_cs);
  float* sdi     = (float*)(ws + o_sdi);

  k_zero<<<1, 1024, 0, stream>>>(cnt, stats);
  k_init<<<577, 256, 0, stream>>>(W1, LPw, wt, e32, E, cnt, W2, cs);
  k_gemm<<<673, 256, 0, stream>>>(x, wt, partial, cnt, E, offs, dinv, cursor);
  k_redplace<<<243, 256, 0, stream>>>(partial, LPb, hcat, e32, E, cursor, srcs);
  k_fuse1<<<NN, 256, 0, stream>>>(offs, srcs, dinv, hcat, b1, W2, hwr, sdi, stats);
  k_fuse2<<<NN, 256, 0, stream>>>(offs, srcs, dinv, hwr, b2, cs, sdi, stats, out);
}